// Round 6
// baseline (220.162 us; speedup 1.0000x reference)
//
#include <hip/hip_runtime.h>

#define DIM 128        // DIN == DOUT
#define D10 12         // DIM/10

typedef __attribute__((ext_vector_type(8))) short bf16x8;
typedef __attribute__((ext_vector_type(4))) float f32x4;

__device__ __forceinline__ void fma4(float4& a, float s, const float4& w) {
    a.x = fmaf(s, w.x, a.x);
    a.y = fmaf(s, w.y, a.y);
    a.z = fmaf(s, w.z, a.z);
    a.w = fmaf(s, w.w, a.w);
}

__device__ __forceinline__ unsigned short f2bf(float f) {
    union { float f; unsigned int u; } v; v.f = f;
    unsigned int u = v.u;
    unsigned int r = (u + 0x7FFFu + ((u >> 16) & 1u)) >> 16;   // RTNE
    return (unsigned short)r;
}

// native memory-side f32 atomic add (no CAS loop, no return dependency)
__device__ __forceinline__ void atomAddF32(float* p, float v) {
    unsafeAtomicAdd(p, v);
}

// ---------------- W transpose + bf16 cast: Wt[n][k] = bf16(W[k][n]) ----------------

__global__ void k_wt(const float* __restrict__ W, unsigned short* __restrict__ Wt) {
    int i = blockIdx.x * 256 + threadIdx.x;
    if (i >= DIM * DIM) return;
    int k = i >> 7, nn = i & 127;
    Wt[nn * DIM + k] = f2bf(W[i]);
}

// ---------------- fused MFMA GEMM ----------------
// s12 = (x@W)[:, :12] raw; out[:, 12:] = prelu((x@W)[:, 12:] + bias)
// 256 thr = 4 waves, 64 rows/block. LDS: x 16KB + Wt 32KB, XOR-swizzled.

__global__ __launch_bounds__(256) void k_gemm(
    const float4* __restrict__ xv, float* __restrict__ out,
    const uint4* __restrict__ Wtv,            // bf16 Wt[n][k]
    const float* __restrict__ bias, const float* __restrict__ alpha,
    float* __restrict__ s12, int n)
{
    __shared__ alignas(16) char lds[48 * 1024];
    char* xs  = lds;            // 64 rows x 128 k x 2B = 16 KB
    char* wsm = lds + 16384;    // 128 n  x 128 k x 2B = 32 KB

    int tid = threadIdx.x;
    int rowbase = blockIdx.x * 64;

#pragma unroll
    for (int ii = 0; ii < 8; ++ii) {
        int i = tid + ii * 256;                  // 2048 x 16B
        int nn = i >> 4, kq = i & 15;
        uint4 v = Wtv[nn * 16 + kq];
        int byte = (nn * 256 + kq * 16) ^ ((nn & 7) << 4);
        *reinterpret_cast<uint4*>(wsm + byte) = v;
    }
#pragma unroll
    for (int ii = 0; ii < 8; ++ii) {
        int i = tid + ii * 256;                  // 2048 x float4
        int lr = i >> 5, c4 = i & 31;
        int r = rowbase + lr;
        float4 v; v.x = v.y = v.z = v.w = 0.f;
        if (r < n) v = xv[(size_t)r * 32 + c4];
        uint2 p;
        p.x = (unsigned int)f2bf(v.x) | ((unsigned int)f2bf(v.y) << 16);
        p.y = (unsigned int)f2bf(v.z) | ((unsigned int)f2bf(v.w) << 16);
        int byte = (lr * 256 + c4 * 8) ^ ((lr & 7) << 4);
        *reinterpret_cast<uint2*>(xs + byte) = p;
    }
    __syncthreads();

    int wv = tid >> 6;
    int lane = tid & 63;
    int lr0 = wv * 16;
    int arow = lr0 + (lane & 15);
    int kgrp = (lane >> 4) * 8;

    f32x4 acc[8];
#pragma unroll
    for (int t = 0; t < 8; ++t) acc[t] = (f32x4){0.f, 0.f, 0.f, 0.f};

#pragma unroll
    for (int kb = 0; kb < 4; ++kb) {
        int koff = kb * 32 + kgrp;
        int abyte = (arow * 256 + koff * 2) ^ ((arow & 7) << 4);
        bf16x8 a = *reinterpret_cast<const bf16x8*>(xs + abyte);
#pragma unroll
        for (int t = 0; t < 8; ++t) {
            int c = t * 16 + (lane & 15);
            int bbyte = (c * 256 + koff * 2) ^ ((c & 7) << 4);
            bf16x8 b = *reinterpret_cast<const bf16x8*>(wsm + bbyte);
            acc[t] = __builtin_amdgcn_mfma_f32_16x16x32_bf16(a, b, acc[t], 0, 0, 0);
        }
    }

    int colbase = lane & 15;
    int rgrp = (lane >> 4) * 4;
    float bi[8], al[8];
#pragma unroll
    for (int t = 0; t < 8; ++t) {
        int c = t * 16 + colbase;
        bi[t] = bias[c];
        al[t] = alpha[c];
    }
#pragma unroll
    for (int j = 0; j < 4; ++j) {
        int r = rowbase + lr0 + rgrp + j;
        if (r >= n) continue;
#pragma unroll
        for (int t = 0; t < 8; ++t) {
            int c = t * 16 + colbase;
            float h = acc[t][j];
            if (t == 0 && colbase < D10) {
                s12[(size_t)r * 12 + colbase] = h;    // raw; epilogue in k_epi12
            } else {
                h += bi[t];
                h = h >= 0.f ? h : al[t] * h;
                out[(size_t)r * DIM + c] = h;
            }
        }
    }
}

// ---------------- edge aggregation: native memory-side fp32 atomics ----------------
// 16 lanes per edge: lanes 0..11 add s12[col] into agg12[row]; lane 12 counts deg.

__global__ void k_edge_agg(const float* __restrict__ s12,
                           const int* __restrict__ row, const int* __restrict__ col,
                           long long total, float* __restrict__ agg12,
                           int* __restrict__ deg) {
    long long i = (long long)blockIdx.x * blockDim.x + threadIdx.x;
    long long stride = (long long)gridDim.x * blockDim.x;
    for (long long g = i; g < total; g += stride) {
        int e = (int)(g >> 4), l = (int)(g & 15);
        int r = row[e];
        if (l < 12) {
            atomAddF32(&agg12[(size_t)r * 12 + l], s12[(size_t)col[e] * 12 + l]);
        } else if (l == 12) {
            atomicAdd(&deg[r], 1);
        }
    }
}

// ---------------- epilogue for cols 0..11: out = prelu(agg/deg + bias) ----------------

__global__ void k_epi12(const float4* __restrict__ aggv, const int* __restrict__ deg,
                        const float* __restrict__ bias, const float* __restrict__ alpha,
                        float* __restrict__ out, int n) {
    int gid = blockIdx.x * blockDim.x + threadIdx.x;
    if (gid >= n * 3) return;
    int r = gid / 3, q = gid - r * 3;
    float4 a = aggv[gid];
    int d = deg[r];
    float invd = 1.f / (float)(d > 0 ? d : 1);
    float4 h;
    h.x = a.x * invd + bias[q * 4 + 0];
    h.y = a.y * invd + bias[q * 4 + 1];
    h.z = a.z * invd + bias[q * 4 + 2];
    h.w = a.w * invd + bias[q * 4 + 3];
    h.x = h.x >= 0.f ? h.x : alpha[q * 4 + 0] * h.x;
    h.y = h.y >= 0.f ? h.y : alpha[q * 4 + 1] * h.y;
    h.z = h.z >= 0.f ? h.z : alpha[q * 4 + 2] * h.z;
    h.w = h.w >= 0.f ? h.w : alpha[q * 4 + 3] * h.w;
    *reinterpret_cast<float4*>(out + (size_t)r * DIM + q * 4) = h;
}

// ---------------- tier E legacy (tiny workspace fallback) ----------------

__global__ void k_count_deg(const int* __restrict__ row, int E, int* __restrict__ deg) {
    int i = blockIdx.x * blockDim.x + threadIdx.x;
    int stride = gridDim.x * blockDim.x;
    for (; i < E; i += stride) atomicAdd(&deg[row[i]], 1);
}

__global__ void k_edge_atomic(const float4* __restrict__ xv, const int* __restrict__ row,
                              const int* __restrict__ col, int E, float* __restrict__ out) {
    int i = blockIdx.x * blockDim.x + threadIdx.x;
    int stride = gridDim.x * blockDim.x;
    int total = E * 32;
    for (; i < total; i += stride) {
        int e = i >> 5, lane = i & 31;
        int r = row[e], c = col[e];
        float4 v = xv[(size_t)c * 32 + lane];
        float* dst = out + (size_t)r * DIM + lane * 4;
        atomAddF32(dst + 0, v.x);
        atomAddF32(dst + 1, v.y);
        atomAddF32(dst + 2, v.z);
        atomAddF32(dst + 3, v.w);
    }
}

__global__ __launch_bounds__(256) void k_final_legacy(const float4* __restrict__ xv,
                                                      float4* __restrict__ outv,
                                                      const float4* __restrict__ Wv,
                                                      const float4* __restrict__ biasv,
                                                      const float4* __restrict__ alphav,
                                                      const int* __restrict__ deg, int n) {
    __shared__ float4 Ws4[DIM * 32];
    __shared__ float4 vs4[2][32 * 32];

    int tid = threadIdx.x;
    int rowbase = blockIdx.x * 32;
    if (rowbase >= n) return;

    for (int i = tid; i < DIM * 32; i += 256) Ws4[i] = Wv[i];
    for (int i = tid; i < 32 * 32; i += 256) {
        int r = rowbase + (i >> 5);
        if (r < n) {
            vs4[0][i] = outv[(size_t)r * 32 + (i & 31)];
            vs4[1][i] = xv[(size_t)r * 32 + (i & 31)];
        }
    }
    __syncthreads();

    int tx = tid & 31;
    int ty = tid >> 5;
    int r0 = ty * 4;
    const float4* V = (tx < (D10 / 4)) ? vs4[0] : vs4[1];

    float4 acc[4];
#pragma unroll
    for (int r = 0; r < 4; r++) { acc[r].x = acc[r].y = acc[r].z = acc[r].w = 0.f; }

#pragma unroll 8
    for (int k4 = 0; k4 < 32; k4++) {
        float4 w0 = Ws4[(k4 * 4 + 0) * 32 + tx];
        float4 w1 = Ws4[(k4 * 4 + 1) * 32 + tx];
        float4 w2 = Ws4[(k4 * 4 + 2) * 32 + tx];
        float4 w3 = Ws4[(k4 * 4 + 3) * 32 + tx];
#pragma unroll
        for (int r = 0; r < 4; r++) {
            float4 v = V[(r0 + r) * 32 + k4];
            fma4(acc[r], v.x, w0); fma4(acc[r], v.y, w1);
            fma4(acc[r], v.z, w2); fma4(acc[r], v.w, w3);
        }
    }

    float4 b4 = biasv[tx];
    float4 a4 = alphav[tx];
#pragma unroll
    for (int r = 0; r < 4; r++) {
        int row = rowbase + r0 + r;
        if (row >= n) continue;
        float4 h = acc[r];
        if (tx < (D10 / 4)) {
            int d = deg[row];
            float invd = 1.0f / (float)(d > 0 ? d : 1);
            h.x *= invd; h.y *= invd; h.z *= invd; h.w *= invd;
        }
        h.x += b4.x; h.y += b4.y; h.z += b4.z; h.w += b4.w;
        h.x = h.x >= 0.f ? h.x : a4.x * h.x;
        h.y = h.y >= 0.f ? h.y : a4.y * h.y;
        h.z = h.z >= 0.f ? h.z : a4.z * h.z;
        h.w = h.w >= 0.f ? h.w : a4.w * h.w;
        outv[(size_t)row * 32 + tx] = h;
    }
}

// ---------------- launcher ----------------

extern "C" void kernel_launch(void* const* d_in, const int* in_sizes, int n_in,
                              void* d_out, int out_size, void* d_ws, size_t ws_size,
                              hipStream_t stream) {
    const float* x     = (const float*)d_in[0];
    const float* W     = (const float*)d_in[1];
    const float* bias  = (const float*)d_in[2];
    const float* alpha = (const float*)d_in[3];
    const int*   ei    = (const int*)d_in[4];

    int N = in_sizes[0] / DIM;
    int E = in_sizes[4] / 2;
    const int* row = ei;
    const int* col = ei + E;
    float* out = (float*)d_out;

    int gemm_blocks = (N + 63) / 64;
    size_t wt_bytes = (size_t)DIM * DIM * 2;   // 32 KB, 16B-aligned

    // Tier A: Wt | s12[12N] | agg12[12N] | deg[N]
    size_t need_A = wt_bytes + (size_t)(12 + 12 + 1) * N * 4;
    size_t need_E = (size_t)N * 4;

    if (ws_size >= need_A) {
        unsigned short* Wt = (unsigned short*)d_ws;
        float* s12   = (float*)((char*)d_ws + wt_bytes);
        float* agg12 = s12 + (size_t)12 * N;
        int*   deg   = (int*)(agg12 + (size_t)12 * N);

        // zero agg12 + deg in one shot (contiguous, 13N words)
        hipMemsetAsync(agg12, 0, (size_t)13 * N * sizeof(float), stream);
        k_wt<<<(DIM * DIM + 255) / 256, 256, 0, stream>>>(W, Wt);
        k_gemm<<<gemm_blocks, 256, 0, stream>>>((const float4*)x, out, (const uint4*)Wt,
                                                bias, alpha, s12, N);
        long long total = (long long)E * 16;
        k_edge_agg<<<4096, 256, 0, stream>>>(s12, row, col, total, agg12, deg);
        k_epi12<<<(3 * N + 255) / 256, 256, 0, stream>>>((const float4*)agg12, deg,
                                                         bias, alpha, out, N);
    } else if (ws_size >= need_E) {
        int* deg = (int*)d_ws;
        hipMemsetAsync(out, 0, (size_t)N * DIM * sizeof(float), stream);
        hipMemsetAsync(deg, 0, (size_t)N * sizeof(int), stream);
        k_count_deg<<<2048, 256, 0, stream>>>(row, E, deg);
        k_edge_atomic<<<4096, 256, 0, stream>>>((const float4*)x, row, col, E, out);
        k_final_legacy<<<(N + 31) / 32, 256, 0, stream>>>((const float4*)x, (float4*)out,
                                                          (const float4*)W, (const float4*)bias,
                                                          (const float4*)alpha, deg, N);
    }
}

// Round 7
// 196.873 us; speedup vs baseline: 1.1183x; 1.1183x over previous
//
#include <hip/hip_runtime.h>

#define DIM 128        // DIN == DOUT
#define D10 12         // DIM/10

typedef __attribute__((ext_vector_type(8))) short bf16x8;
typedef __attribute__((ext_vector_type(4))) float f32x4;

__device__ __forceinline__ void fma4(float4& a, float s, const float4& w) {
    a.x = fmaf(s, w.x, a.x);
    a.y = fmaf(s, w.y, a.y);
    a.z = fmaf(s, w.z, a.z);
    a.w = fmaf(s, w.w, a.w);
}

__device__ __forceinline__ unsigned short f2bf(float f) {
    union { float f; unsigned int u; } v; v.f = f;
    unsigned int u = v.u;
    unsigned int r = (u + 0x7FFFu + ((u >> 16) & 1u)) >> 16;   // RTNE
    return (unsigned short)r;
}

__device__ __forceinline__ float bf2f(unsigned int hi16) {
    union { unsigned int u; float f; } v; v.u = hi16 << 16;
    return v.f;
}

// packed 2x bf16 atomic add (memory-side, fire-and-forget)
__device__ __forceinline__ void atomPkAddBf16(unsigned int* p, unsigned int v) {
    unsigned long long a = (unsigned long long)p;
    asm volatile("global_atomic_pk_add_bf16 %0, %1, off" :: "v"(a), "v"(v) : "memory");
}

// native memory-side f32 atomic add (tier E fallback)
__device__ __forceinline__ void atomAddF32(float* p, float v) {
    unsafeAtomicAdd(p, v);
}

// ---------------- W transpose + bf16 cast: Wt[n][k] = bf16(W[k][n]) ----------------

__global__ void k_wt(const float* __restrict__ W, unsigned short* __restrict__ Wt) {
    int i = blockIdx.x * 256 + threadIdx.x;
    if (i >= DIM * DIM) return;
    int k = i >> 7, nn = i & 127;
    Wt[nn * DIM + k] = f2bf(W[i]);
}

// ---------------- fused MFMA GEMM ----------------
// s12b = packed bf16x2 of (x@W)[:, :12]; out[:, 12:] = prelu((x@W)[:, 12:] + bias)
// 256 thr = 4 waves, 64 rows/block. LDS: x 16KB + Wt 32KB, XOR-swizzled.

__global__ __launch_bounds__(256) void k_gemm(
    const float4* __restrict__ xv, float* __restrict__ out,
    const uint4* __restrict__ Wtv,            // bf16 Wt[n][k]
    const float* __restrict__ bias, const float* __restrict__ alpha,
    unsigned int* __restrict__ s12b, int n)
{
    __shared__ alignas(16) char lds[48 * 1024];
    char* xs  = lds;            // 64 rows x 128 k x 2B = 16 KB
    char* wsm = lds + 16384;    // 128 n  x 128 k x 2B = 32 KB

    int tid = threadIdx.x;
    int rowbase = blockIdx.x * 64;

#pragma unroll
    for (int ii = 0; ii < 8; ++ii) {
        int i = tid + ii * 256;                  // 2048 x 16B
        int nn = i >> 4, kq = i & 15;
        uint4 v = Wtv[nn * 16 + kq];
        int byte = (nn * 256 + kq * 16) ^ ((nn & 7) << 4);
        *reinterpret_cast<uint4*>(wsm + byte) = v;
    }
#pragma unroll
    for (int ii = 0; ii < 8; ++ii) {
        int i = tid + ii * 256;                  // 2048 x float4
        int lr = i >> 5, c4 = i & 31;
        int r = rowbase + lr;
        float4 v; v.x = v.y = v.z = v.w = 0.f;
        if (r < n) v = xv[(size_t)r * 32 + c4];
        uint2 p;
        p.x = (unsigned int)f2bf(v.x) | ((unsigned int)f2bf(v.y) << 16);
        p.y = (unsigned int)f2bf(v.z) | ((unsigned int)f2bf(v.w) << 16);
        int byte = (lr * 256 + c4 * 8) ^ ((lr & 7) << 4);
        *reinterpret_cast<uint2*>(xs + byte) = p;
    }
    __syncthreads();

    int wv = tid >> 6;
    int lane = tid & 63;
    int lr0 = wv * 16;
    int arow = lr0 + (lane & 15);
    int kgrp = (lane >> 4) * 8;

    f32x4 acc[8];
#pragma unroll
    for (int t = 0; t < 8; ++t) acc[t] = (f32x4){0.f, 0.f, 0.f, 0.f};

#pragma unroll
    for (int kb = 0; kb < 4; ++kb) {
        int koff = kb * 32 + kgrp;
        int abyte = (arow * 256 + koff * 2) ^ ((arow & 7) << 4);
        bf16x8 a = *reinterpret_cast<const bf16x8*>(xs + abyte);
#pragma unroll
        for (int t = 0; t < 8; ++t) {
            int c = t * 16 + (lane & 15);
            int bbyte = (c * 256 + koff * 2) ^ ((c & 7) << 4);
            bf16x8 b = *reinterpret_cast<const bf16x8*>(wsm + bbyte);
            acc[t] = __builtin_amdgcn_mfma_f32_16x16x32_bf16(a, b, acc[t], 0, 0, 0);
        }
    }

    // C/D layout: col=lane&15, row=(lane>>4)*4+reg
    int colbase = lane & 15;
    int rgrp = (lane >> 4) * 4;
    float bi[8], al[8];
#pragma unroll
    for (int t = 0; t < 8; ++t) {
        int c = t * 16 + colbase;
        bi[t] = bias[c];
        al[t] = alpha[c];
    }
#pragma unroll
    for (int j = 0; j < 4; ++j) {
        int r = rowbase + lr0 + rgrp + j;
        if (r >= n) continue;
#pragma unroll
        for (int t = 0; t < 8; ++t) {
            int c = t * 16 + colbase;
            float h = acc[t][j];
            if (t == 0 && colbase < D10) {
                // pack pairs (c even gets c,c+1) — partner lane shares r
                float h1 = __shfl_xor(h, 1, 64);
                if ((colbase & 1) == 0) {
                    unsigned int pk = (unsigned int)f2bf(h) |
                                      ((unsigned int)f2bf(h1) << 16);
                    s12b[(size_t)r * 6 + (colbase >> 1)] = pk;
                }
            } else {
                h += bi[t];
                h = h >= 0.f ? h : al[t] * h;
                out[(size_t)r * DIM + c] = h;
            }
        }
    }
}

// ---------------- edge aggregation: packed bf16x2 atomics ----------------
// 8 lanes per edge: lanes 0..5 pk-add s12b[col] into agg12b[row]; lane 6 counts deg.

__global__ void k_edge_agg(const unsigned int* __restrict__ s12b,
                           const int* __restrict__ row, const int* __restrict__ col,
                           long long total, unsigned int* __restrict__ agg12b,
                           int* __restrict__ deg) {
    long long i = (long long)blockIdx.x * blockDim.x + threadIdx.x;
    long long stride = (long long)gridDim.x * blockDim.x;
    for (long long g = i; g < total; g += stride) {
        int e = (int)(g >> 3), l = (int)(g & 7);
        int r = row[e];
        if (l < 6) {
            unsigned int v = s12b[(size_t)col[e] * 6 + l];
            atomPkAddBf16(&agg12b[(size_t)r * 6 + l], v);
        } else if (l == 6) {
            atomicAdd(&deg[r], 1);
        }
    }
}

// ---------------- epilogue for cols 0..11: out = prelu(agg/deg + bias) ----------------

__global__ void k_epi12(const unsigned int* __restrict__ aggb, const int* __restrict__ deg,
                        const float* __restrict__ bias, const float* __restrict__ alpha,
                        float* __restrict__ out, int n) {
    int r = blockIdx.x * blockDim.x + threadIdx.x;
    if (r >= n) return;
    int d = deg[r];
    float invd = 1.f / (float)(d > 0 ? d : 1);
    float h[12];
#pragma unroll
    for (int q = 0; q < 6; ++q) {
        unsigned int u = aggb[(size_t)r * 6 + q];
        h[2 * q]     = bf2f(u & 0xFFFFu) * invd + bias[2 * q];
        h[2 * q + 1] = bf2f(u >> 16)     * invd + bias[2 * q + 1];
    }
#pragma unroll
    for (int c = 0; c < 12; ++c) {
        float v = h[c];
        h[c] = v >= 0.f ? v : alpha[c] * v;
    }
    float4* o = reinterpret_cast<float4*>(out + (size_t)r * DIM);
    o[0] = make_float4(h[0], h[1], h[2], h[3]);
    o[1] = make_float4(h[4], h[5], h[6], h[7]);
    o[2] = make_float4(h[8], h[9], h[10], h[11]);
}

// ---------------- tier E legacy (tiny workspace fallback) ----------------

__global__ void k_count_deg(const int* __restrict__ row, int E, int* __restrict__ deg) {
    int i = blockIdx.x * blockDim.x + threadIdx.x;
    int stride = gridDim.x * blockDim.x;
    for (; i < E; i += stride) atomicAdd(&deg[row[i]], 1);
}

__global__ void k_edge_atomic(const float4* __restrict__ xv, const int* __restrict__ row,
                              const int* __restrict__ col, int E, float* __restrict__ out) {
    int i = blockIdx.x * blockDim.x + threadIdx.x;
    int stride = gridDim.x * blockDim.x;
    int total = E * 32;
    for (; i < total; i += stride) {
        int e = i >> 5, lane = i & 31;
        int r = row[e], c = col[e];
        float4 v = xv[(size_t)c * 32 + lane];
        float* dst = out + (size_t)r * DIM + lane * 4;
        atomAddF32(dst + 0, v.x);
        atomAddF32(dst + 1, v.y);
        atomAddF32(dst + 2, v.z);
        atomAddF32(dst + 3, v.w);
    }
}

__global__ __launch_bounds__(256) void k_final_legacy(const float4* __restrict__ xv,
                                                      float4* __restrict__ outv,
                                                      const float4* __restrict__ Wv,
                                                      const float4* __restrict__ biasv,
                                                      const float4* __restrict__ alphav,
                                                      const int* __restrict__ deg, int n) {
    __shared__ float4 Ws4[DIM * 32];
    __shared__ float4 vs4[2][32 * 32];

    int tid = threadIdx.x;
    int rowbase = blockIdx.x * 32;
    if (rowbase >= n) return;

    for (int i = tid; i < DIM * 32; i += 256) Ws4[i] = Wv[i];
    for (int i = tid; i < 32 * 32; i += 256) {
        int r = rowbase + (i >> 5);
        if (r < n) {
            vs4[0][i] = outv[(size_t)r * 32 + (i & 31)];
            vs4[1][i] = xv[(size_t)r * 32 + (i & 31)];
        }
    }
    __syncthreads();

    int tx = tid & 31;
    int ty = tid >> 5;
    int r0 = ty * 4;
    const float4* V = (tx < (D10 / 4)) ? vs4[0] : vs4[1];

    float4 acc[4];
#pragma unroll
    for (int r = 0; r < 4; r++) { acc[r].x = acc[r].y = acc[r].z = acc[r].w = 0.f; }

#pragma unroll 8
    for (int k4 = 0; k4 < 32; k4++) {
        float4 w0 = Ws4[(k4 * 4 + 0) * 32 + tx];
        float4 w1 = Ws4[(k4 * 4 + 1) * 32 + tx];
        float4 w2 = Ws4[(k4 * 4 + 2) * 32 + tx];
        float4 w3 = Ws4[(k4 * 4 + 3) * 32 + tx];
#pragma unroll
        for (int r = 0; r < 4; r++) {
            float4 v = V[(r0 + r) * 32 + k4];
            fma4(acc[r], v.x, w0); fma4(acc[r], v.y, w1);
            fma4(acc[r], v.z, w2); fma4(acc[r], v.w, w3);
        }
    }

    float4 b4 = biasv[tx];
    float4 a4 = alphav[tx];
#pragma unroll
    for (int r = 0; r < 4; r++) {
        int row = rowbase + r0 + r;
        if (row >= n) continue;
        float4 h = acc[r];
        if (tx < (D10 / 4)) {
            int d = deg[row];
            float invd = 1.0f / (float)(d > 0 ? d : 1);
            h.x *= invd; h.y *= invd; h.z *= invd; h.w *= invd;
        }
        h.x += b4.x; h.y += b4.y; h.z += b4.z; h.w += b4.w;
        h.x = h.x >= 0.f ? h.x : a4.x * h.x;
        h.y = h.y >= 0.f ? h.y : a4.y * h.y;
        h.z = h.z >= 0.f ? h.z : a4.z * h.z;
        h.w = h.w >= 0.f ? h.w : a4.w * h.w;
        outv[(size_t)row * 32 + tx] = h;
    }
}

// ---------------- launcher ----------------

extern "C" void kernel_launch(void* const* d_in, const int* in_sizes, int n_in,
                              void* d_out, int out_size, void* d_ws, size_t ws_size,
                              hipStream_t stream) {
    const float* x     = (const float*)d_in[0];
    const float* W     = (const float*)d_in[1];
    const float* bias  = (const float*)d_in[2];
    const float* alpha = (const float*)d_in[3];
    const int*   ei    = (const int*)d_in[4];

    int N = in_sizes[0] / DIM;
    int E = in_sizes[4] / 2;
    const int* row = ei;
    const int* col = ei + E;
    float* out = (float*)d_out;

    int gemm_blocks = (N + 63) / 64;
    size_t wt_bytes = (size_t)DIM * DIM * 2;   // 32 KB, 16B-aligned

    // Tier A: Wt | s12b[6N] u32 | agg12b[6N] u32 | deg[N]
    size_t need_A = wt_bytes + (size_t)(6 + 6 + 1) * N * 4;
    size_t need_E = (size_t)N * 4;

    if (ws_size >= need_A) {
        unsigned short* Wt   = (unsigned short*)d_ws;
        unsigned int* s12b   = (unsigned int*)((char*)d_ws + wt_bytes);
        unsigned int* agg12b = s12b + (size_t)6 * N;
        int*          deg    = (int*)(agg12b + (size_t)6 * N);

        // zero agg12b + deg in one shot (contiguous, 7N words)
        hipMemsetAsync(agg12b, 0, (size_t)7 * N * sizeof(int), stream);
        k_wt<<<(DIM * DIM + 255) / 256, 256, 0, stream>>>(W, Wt);
        k_gemm<<<gemm_blocks, 256, 0, stream>>>((const float4*)x, out, (const uint4*)Wt,
                                                bias, alpha, s12b, N);
        long long total = (long long)E * 8;
        k_edge_agg<<<4096, 256, 0, stream>>>(s12b, row, col, total, agg12b, deg);
        k_epi12<<<(N + 255) / 256, 256, 0, stream>>>(agg12b, deg, bias, alpha, out, N);
    } else if (ws_size >= need_E) {
        int* deg = (int*)d_ws;
        hipMemsetAsync(out, 0, (size_t)N * DIM * sizeof(float), stream);
        hipMemsetAsync(deg, 0, (size_t)N * sizeof(int), stream);
        k_count_deg<<<2048, 256, 0, stream>>>(row, E, deg);
        k_edge_atomic<<<4096, 256, 0, stream>>>((const float4*)x, row, col, E, out);
        k_final_legacy<<<(N + 31) / 32, 256, 0, stream>>>((const float4*)x, (float4*)out,
                                                          (const float4*)W, (const float4*)bias,
                                                          (const float4*)alpha, deg, N);
    }
}

// Round 8
// 155.133 us; speedup vs baseline: 1.4192x; 1.2691x over previous
//
#include <hip/hip_runtime.h>

#define DIM 128        // DIN == DOUT
#define D10 12         // DIM/10

typedef __attribute__((ext_vector_type(8))) short bf16x8;
typedef __attribute__((ext_vector_type(4))) float f32x4;

__device__ __forceinline__ void fma4(float4& a, float s, const float4& w) {
    a.x = fmaf(s, w.x, a.x);
    a.y = fmaf(s, w.y, a.y);
    a.z = fmaf(s, w.z, a.z);
    a.w = fmaf(s, w.w, a.w);
}

__device__ __forceinline__ unsigned short f2bf(float f) {
    union { float f; unsigned int u; } v; v.f = f;
    unsigned int u = v.u;
    unsigned int r = (u + 0x7FFFu + ((u >> 16) & 1u)) >> 16;   // RTNE
    return (unsigned short)r;
}

__device__ __forceinline__ float bf2f(unsigned int hi16) {
    union { unsigned int u; float f; } v; v.u = hi16 << 16;
    return v.f;
}

__device__ __forceinline__ void atomAddF32(float* p, float v) {
    unsafeAtomicAdd(p, v);
}

// ---------------- W transpose + bf16 cast: Wt[n][k] = bf16(W[k][n]) ----------------

__global__ void k_wt(const float* __restrict__ W, unsigned short* __restrict__ Wt) {
    int i = blockIdx.x * 256 + threadIdx.x;
    if (i >= DIM * DIM) return;
    int k = i >> 7, nn = i & 127;
    Wt[nn * DIM + k] = f2bf(W[i]);
}

// ---------------- fused MFMA GEMM ----------------
// s12b = packed bf16x2 of (x@W)[:, :12]; out[:, 12:] = prelu((x@W)[:, 12:] + bias)
// 256 thr = 4 waves, 64 rows/block. LDS: x 16KB + Wt 32KB, XOR-swizzled.

__global__ __launch_bounds__(256) void k_gemm(
    const float4* __restrict__ xv, float* __restrict__ out,
    const uint4* __restrict__ Wtv,            // bf16 Wt[n][k]
    const float* __restrict__ bias, const float* __restrict__ alpha,
    unsigned int* __restrict__ s12b, int n)
{
    __shared__ alignas(16) char lds[48 * 1024];
    char* xs  = lds;            // 64 rows x 128 k x 2B = 16 KB
    char* wsm = lds + 16384;    // 128 n  x 128 k x 2B = 32 KB

    int tid = threadIdx.x;
    int rowbase = blockIdx.x * 64;

#pragma unroll
    for (int ii = 0; ii < 8; ++ii) {
        int i = tid + ii * 256;                  // 2048 x 16B
        int nn = i >> 4, kq = i & 15;
        uint4 v = Wtv[nn * 16 + kq];
        int byte = (nn * 256 + kq * 16) ^ ((nn & 7) << 4);
        *reinterpret_cast<uint4*>(wsm + byte) = v;
    }
#pragma unroll
    for (int ii = 0; ii < 8; ++ii) {
        int i = tid + ii * 256;                  // 2048 x float4
        int lr = i >> 5, c4 = i & 31;
        int r = rowbase + lr;
        float4 v; v.x = v.y = v.z = v.w = 0.f;
        if (r < n) v = xv[(size_t)r * 32 + c4];
        uint2 p;
        p.x = (unsigned int)f2bf(v.x) | ((unsigned int)f2bf(v.y) << 16);
        p.y = (unsigned int)f2bf(v.z) | ((unsigned int)f2bf(v.w) << 16);
        int byte = (lr * 256 + c4 * 8) ^ ((lr & 7) << 4);
        *reinterpret_cast<uint2*>(xs + byte) = p;
    }
    __syncthreads();

    int wv = tid >> 6;
    int lane = tid & 63;
    int lr0 = wv * 16;
    int arow = lr0 + (lane & 15);
    int kgrp = (lane >> 4) * 8;

    f32x4 acc[8];
#pragma unroll
    for (int t = 0; t < 8; ++t) acc[t] = (f32x4){0.f, 0.f, 0.f, 0.f};

#pragma unroll
    for (int kb = 0; kb < 4; ++kb) {
        int koff = kb * 32 + kgrp;
        int abyte = (arow * 256 + koff * 2) ^ ((arow & 7) << 4);
        bf16x8 a = *reinterpret_cast<const bf16x8*>(xs + abyte);
#pragma unroll
        for (int t = 0; t < 8; ++t) {
            int c = t * 16 + (lane & 15);
            int bbyte = (c * 256 + koff * 2) ^ ((c & 7) << 4);
            bf16x8 b = *reinterpret_cast<const bf16x8*>(wsm + bbyte);
            acc[t] = __builtin_amdgcn_mfma_f32_16x16x32_bf16(a, b, acc[t], 0, 0, 0);
        }
    }

    // C/D layout: col=lane&15, row=(lane>>4)*4+reg
    int colbase = lane & 15;
    int rgrp = (lane >> 4) * 4;
    float bi[8], al[8];
#pragma unroll
    for (int t = 0; t < 8; ++t) {
        int c = t * 16 + colbase;
        bi[t] = bias[c];
        al[t] = alpha[c];
    }
#pragma unroll
    for (int j = 0; j < 4; ++j) {
        int r = rowbase + lr0 + rgrp + j;
        if (r >= n) continue;
#pragma unroll
        for (int t = 0; t < 8; ++t) {
            int c = t * 16 + colbase;
            float h = acc[t][j];
            if (t == 0 && colbase < D10) {
                // pack pairs (even colbase keeps c,c+1) — partner lane shares r
                float h1 = __shfl_xor(h, 1, 64);
                if ((colbase & 1) == 0) {
                    unsigned int pk = (unsigned int)f2bf(h) |
                                      ((unsigned int)f2bf(h1) << 16);
                    s12b[(size_t)r * 6 + (colbase >> 1)] = pk;
                }
            } else {
                h += bi[t];
                h = h >= 0.f ? h : al[t] * h;
                out[(size_t)r * DIM + c] = h;
            }
        }
    }
}

// ---------------- CSR build: count+pos, 3-kernel scan, scatter ----------------

__global__ void k_count_pos(const int* __restrict__ row, int E,
                            int* __restrict__ deg, int* __restrict__ pos) {
    int i = blockIdx.x * blockDim.x + threadIdx.x;
    int stride = gridDim.x * blockDim.x;
    for (; i < E; i += stride) pos[i] = atomicAdd(&deg[row[i]], 1);
}

__global__ void k_block_sums(const int* __restrict__ deg, int n, int* __restrict__ bsum) {
    __shared__ int s[256];
    int b = blockIdx.x, t = threadIdx.x;
    int base = b * 2048 + t * 8;
    int local = 0;
#pragma unroll
    for (int j = 0; j < 8; j++) { int idx = base + j; if (idx < n) local += deg[idx]; }
    s[t] = local; __syncthreads();
    for (int off = 128; off > 0; off >>= 1) { if (t < off) s[t] += s[t + off]; __syncthreads(); }
    if (t == 0) bsum[b] = s[0];
}

__global__ void k_scan_small(const int* __restrict__ bsum, int G, int* __restrict__ boffs) {
    __shared__ int s[128];
    int t = threadIdx.x;
    int v = (t < G) ? bsum[t] : 0;
    s[t] = v; __syncthreads();
    for (int off = 1; off < 128; off <<= 1) {
        int u = (t >= off) ? s[t - off] : 0;
        __syncthreads();
        s[t] += u;
        __syncthreads();
    }
    if (t < G) boffs[t] = s[t] - v;
}

__global__ void k_scan_write(const int* __restrict__ deg, int n,
                             const int* __restrict__ boffs, int* __restrict__ offs) {
    __shared__ int s[256];
    int b = blockIdx.x, t = threadIdx.x;
    int base = b * 2048 + t * 8;
    int vals[8];
    int local = 0;
#pragma unroll
    for (int j = 0; j < 8; j++) {
        int idx = base + j;
        vals[j] = (idx < n) ? deg[idx] : 0;
        local += vals[j];
    }
    s[t] = local; __syncthreads();
    for (int off = 1; off < 256; off <<= 1) {
        int u = (t >= off) ? s[t - off] : 0;
        __syncthreads();
        s[t] += u;
        __syncthreads();
    }
    int run = s[t] - local + boffs[b];
#pragma unroll
    for (int j = 0; j < 8; j++) {
        int idx = base + j;
        if (idx < n) {
            offs[idx] = run;
            run += vals[j];
            if (idx == n - 1) offs[n] = run;
        }
    }
}

__global__ void k_scatter(const int* __restrict__ row, const int* __restrict__ col, int E,
                          const int* __restrict__ offs, const int* __restrict__ pos,
                          int* __restrict__ csr) {
    int i = blockIdx.x * blockDim.x + threadIdx.x;
    int stride = gridDim.x * blockDim.x;
    for (; i < E; i += stride) csr[offs[row[i]] + pos[i]] = col[i];
}

// ---------------- gather + fused epilogue for cols 0..11 ----------------
// 8 lanes per node; lanes 0..5 own column-pair sub; f32 accumulation.

__global__ __launch_bounds__(256) void k_gather(
    const unsigned int* __restrict__ s12b, const int* __restrict__ csr,
    const int* __restrict__ offs,
    const float* __restrict__ bias, const float* __restrict__ alpha,
    float* __restrict__ out, int n)
{
    int t = blockIdx.x * 256 + threadIdx.x;
    int node = t >> 3, sub = t & 7;
    if (node >= n || sub >= 6) return;

    int s = offs[node], e = offs[node + 1];
    float alo = 0.f, ahi = 0.f;
    for (int j = s; j < e; ++j) {
        int c = csr[j];                              // broadcast across 6 lanes
        unsigned int u = s12b[(size_t)c * 6 + sub];  // 24B contiguous per edge
        alo += bf2f(u & 0xFFFFu);
        ahi += bf2f(u >> 16);
    }
    int d = e - s;
    float invd = 1.f / (float)(d > 0 ? d : 1);
    float h0 = alo * invd + bias[2 * sub];
    float h1 = ahi * invd + bias[2 * sub + 1];
    h0 = h0 >= 0.f ? h0 : alpha[2 * sub] * h0;
    h1 = h1 >= 0.f ? h1 : alpha[2 * sub + 1] * h1;
    float2 o = make_float2(h0, h1);
    *reinterpret_cast<float2*>(out + (size_t)node * DIM + 2 * sub) = o;
}

// ---------------- tier E legacy (tiny workspace fallback) ----------------

__global__ void k_count_deg(const int* __restrict__ row, int E, int* __restrict__ deg) {
    int i = blockIdx.x * blockDim.x + threadIdx.x;
    int stride = gridDim.x * blockDim.x;
    for (; i < E; i += stride) atomicAdd(&deg[row[i]], 1);
}

__global__ void k_edge_atomic(const float4* __restrict__ xv, const int* __restrict__ row,
                              const int* __restrict__ col, int E, float* __restrict__ out) {
    int i = blockIdx.x * blockDim.x + threadIdx.x;
    int stride = gridDim.x * blockDim.x;
    int total = E * 32;
    for (; i < total; i += stride) {
        int e = i >> 5, lane = i & 31;
        int r = row[e], c = col[e];
        float4 v = xv[(size_t)c * 32 + lane];
        float* dst = out + (size_t)r * DIM + lane * 4;
        atomAddF32(dst + 0, v.x);
        atomAddF32(dst + 1, v.y);
        atomAddF32(dst + 2, v.z);
        atomAddF32(dst + 3, v.w);
    }
}

__global__ __launch_bounds__(256) void k_final_legacy(const float4* __restrict__ xv,
                                                      float4* __restrict__ outv,
                                                      const float4* __restrict__ Wv,
                                                      const float4* __restrict__ biasv,
                                                      const float4* __restrict__ alphav,
                                                      const int* __restrict__ deg, int n) {
    __shared__ float4 Ws4[DIM * 32];
    __shared__ float4 vs4[2][32 * 32];

    int tid = threadIdx.x;
    int rowbase = blockIdx.x * 32;
    if (rowbase >= n) return;

    for (int i = tid; i < DIM * 32; i += 256) Ws4[i] = Wv[i];
    for (int i = tid; i < 32 * 32; i += 256) {
        int r = rowbase + (i >> 5);
        if (r < n) {
            vs4[0][i] = outv[(size_t)r * 32 + (i & 31)];
            vs4[1][i] = xv[(size_t)r * 32 + (i & 31)];
        }
    }
    __syncthreads();

    int tx = tid & 31;
    int ty = tid >> 5;
    int r0 = ty * 4;
    const float4* V = (tx < (D10 / 4)) ? vs4[0] : vs4[1];

    float4 acc[4];
#pragma unroll
    for (int r = 0; r < 4; r++) { acc[r].x = acc[r].y = acc[r].z = acc[r].w = 0.f; }

#pragma unroll 8
    for (int k4 = 0; k4 < 32; k4++) {
        float4 w0 = Ws4[(k4 * 4 + 0) * 32 + tx];
        float4 w1 = Ws4[(k4 * 4 + 1) * 32 + tx];
        float4 w2 = Ws4[(k4 * 4 + 2) * 32 + tx];
        float4 w3 = Ws4[(k4 * 4 + 3) * 32 + tx];
#pragma unroll
        for (int r = 0; r < 4; r++) {
            float4 v = V[(r0 + r) * 32 + k4];
            fma4(acc[r], v.x, w0); fma4(acc[r], v.y, w1);
            fma4(acc[r], v.z, w2); fma4(acc[r], v.w, w3);
        }
    }

    float4 b4 = biasv[tx];
    float4 a4 = alphav[tx];
#pragma unroll
    for (int r = 0; r < 4; r++) {
        int row = rowbase + r0 + r;
        if (row >= n) continue;
        float4 h = acc[r];
        if (tx < (D10 / 4)) {
            int d = deg[row];
            float invd = 1.0f / (float)(d > 0 ? d : 1);
            h.x *= invd; h.y *= invd; h.z *= invd; h.w *= invd;
        }
        h.x += b4.x; h.y += b4.y; h.z += b4.z; h.w += b4.w;
        h.x = h.x >= 0.f ? h.x : a4.x * h.x;
        h.y = h.y >= 0.f ? h.y : a4.y * h.y;
        h.z = h.z >= 0.f ? h.z : a4.z * h.z;
        h.w = h.w >= 0.f ? h.w : a4.w * h.w;
        outv[(size_t)row * 32 + tx] = h;
    }
}

// ---------------- launcher ----------------

extern "C" void kernel_launch(void* const* d_in, const int* in_sizes, int n_in,
                              void* d_out, int out_size, void* d_ws, size_t ws_size,
                              hipStream_t stream) {
    const float* x     = (const float*)d_in[0];
    const float* W     = (const float*)d_in[1];
    const float* bias  = (const float*)d_in[2];
    const float* alpha = (const float*)d_in[3];
    const int*   ei    = (const int*)d_in[4];

    int N = in_sizes[0] / DIM;
    int E = in_sizes[4] / 2;
    const int* row = ei;
    const int* col = ei + E;
    float* out = (float*)d_out;

    int gemm_blocks = (N + 63) / 64;
    int G = (N + 2047) / 2048;                 // scan blocks (49 for N=100000)
    size_t wt_bytes = (size_t)DIM * DIM * 2;   // 32 KB, 16B-aligned

    // Tier A: Wt | s12b[6N] | deg[N] | offs[N+1] | pos[E] | csr[E] | bsum[G] | boffs[G]
    size_t need_A = wt_bytes + ((size_t)7 * N + 1 + 2 * (size_t)E + 2 * G) * 4;
    size_t need_E = (size_t)N * 4;

    if (G <= 128 && ws_size >= need_A) {
        unsigned short* Wt   = (unsigned short*)d_ws;
        unsigned int* s12b   = (unsigned int*)((char*)d_ws + wt_bytes);
        int*          deg    = (int*)(s12b + (size_t)6 * N);
        int*          offs   = deg + N;
        int*          pos    = offs + N + 1;
        int*          csr    = pos + E;
        int*          bsum   = csr + E;
        int*          boffs  = bsum + G;

        hipMemsetAsync(deg, 0, (size_t)N * sizeof(int), stream);
        k_wt<<<(DIM * DIM + 255) / 256, 256, 0, stream>>>(W, Wt);
        k_gemm<<<gemm_blocks, 256, 0, stream>>>((const float4*)x, out, (const uint4*)Wt,
                                                bias, alpha, s12b, N);
        k_count_pos<<<2048, 256, 0, stream>>>(row, E, deg, pos);
        k_block_sums<<<G, 256, 0, stream>>>(deg, N, bsum);
        k_scan_small<<<1, 128, 0, stream>>>(bsum, G, boffs);
        k_scan_write<<<G, 256, 0, stream>>>(deg, N, boffs, offs);
        k_scatter<<<2048, 256, 0, stream>>>(row, col, E, offs, pos, csr);
        k_gather<<<(N * 8 + 255) / 256, 256, 0, stream>>>(s12b, csr, offs,
                                                          bias, alpha, out, N);
    } else if (ws_size >= need_E) {
        int* deg = (int*)d_ws;
        hipMemsetAsync(out, 0, (size_t)N * DIM * sizeof(float), stream);
        hipMemsetAsync(deg, 0, (size_t)N * sizeof(int), stream);
        k_count_deg<<<2048, 256, 0, stream>>>(row, E, deg);
        k_edge_atomic<<<4096, 256, 0, stream>>>((const float4*)x, row, col, E, out);
        k_final_legacy<<<(N + 31) / 32, 256, 0, stream>>>((const float4*)x, (float4*)out,
                                                          (const float4*)W, (const float4*)bias,
                                                          (const float4*)alpha, deg, N);
    }
}

// Round 9
// 119.870 us; speedup vs baseline: 1.8367x; 1.2942x over previous
//
#include <hip/hip_runtime.h>

#define DIM 128        // DIN == DOUT
#define D10 12         // DIM/10

typedef __attribute__((ext_vector_type(8))) short bf16x8;
typedef __attribute__((ext_vector_type(4))) float f32x4;

__device__ __forceinline__ void fma4(float4& a, float s, const float4& w) {
    a.x = fmaf(s, w.x, a.x);
    a.y = fmaf(s, w.y, a.y);
    a.z = fmaf(s, w.z, a.z);
    a.w = fmaf(s, w.w, a.w);
}

__device__ __forceinline__ unsigned short f2bf(float f) {
    union { float f; unsigned int u; } v; v.f = f;
    unsigned int u = v.u;
    unsigned int r = (u + 0x7FFFu + ((u >> 16) & 1u)) >> 16;   // RTNE
    return (unsigned short)r;
}

__device__ __forceinline__ float bf2f(unsigned int hi16) {
    union { unsigned int u; float f; } v; v.u = hi16 << 16;
    return v.f;
}

// packed 2x bf16 atomic add (memory-side, fire-and-forget)
__device__ __forceinline__ void atomPkAddBf16(unsigned int* p, unsigned int v) {
    unsigned long long a = (unsigned long long)p;
    asm volatile("global_atomic_pk_add_bf16 %0, %1, off" :: "v"(a), "v"(v) : "memory");
}

__device__ __forceinline__ void atomAddF32(float* p, float v) {
    unsafeAtomicAdd(p, v);
}

// ---------------- W transpose + bf16 cast: Wt[n][k] = bf16(W[k][n]) ----------------

__global__ void k_wt(const float* __restrict__ W, unsigned short* __restrict__ Wt) {
    int i = blockIdx.x * 256 + threadIdx.x;
    if (i >= DIM * DIM) return;
    int k = i >> 7, nn = i & 127;
    Wt[nn * DIM + k] = f2bf(W[i]);
}

// ---------------- fused MFMA GEMM ----------------
// s12b = packed bf16x2 of (x@W)[:, :12]; out[:, 12:] = prelu((x@W)[:, 12:] + bias)
// 256 thr = 4 waves, 64 rows/block. LDS: x 16KB + Wt 32KB, XOR-swizzled.

__global__ __launch_bounds__(256) void k_gemm(
    const float4* __restrict__ xv, float* __restrict__ out,
    const uint4* __restrict__ Wtv,            // bf16 Wt[n][k]
    const float* __restrict__ bias, const float* __restrict__ alpha,
    unsigned int* __restrict__ s12b, int n)
{
    __shared__ alignas(16) char lds[48 * 1024];
    char* xs  = lds;            // 64 rows x 128 k x 2B = 16 KB
    char* wsm = lds + 16384;    // 128 n  x 128 k x 2B = 32 KB

    int tid = threadIdx.x;
    int rowbase = blockIdx.x * 64;

#pragma unroll
    for (int ii = 0; ii < 8; ++ii) {
        int i = tid + ii * 256;                  // 2048 x 16B
        int nn = i >> 4, kq = i & 15;
        uint4 v = Wtv[nn * 16 + kq];
        int byte = (nn * 256 + kq * 16) ^ ((nn & 7) << 4);
        *reinterpret_cast<uint4*>(wsm + byte) = v;
    }
#pragma unroll
    for (int ii = 0; ii < 8; ++ii) {
        int i = tid + ii * 256;                  // 2048 x float4
        int lr = i >> 5, c4 = i & 31;
        int r = rowbase + lr;
        float4 v; v.x = v.y = v.z = v.w = 0.f;
        if (r < n) v = xv[(size_t)r * 32 + c4];
        uint2 p;
        p.x = (unsigned int)f2bf(v.x) | ((unsigned int)f2bf(v.y) << 16);
        p.y = (unsigned int)f2bf(v.z) | ((unsigned int)f2bf(v.w) << 16);
        int byte = (lr * 256 + c4 * 8) ^ ((lr & 7) << 4);
        *reinterpret_cast<uint2*>(xs + byte) = p;
    }
    __syncthreads();

    int wv = tid >> 6;
    int lane = tid & 63;
    int lr0 = wv * 16;
    int arow = lr0 + (lane & 15);
    int kgrp = (lane >> 4) * 8;

    f32x4 acc[8];
#pragma unroll
    for (int t = 0; t < 8; ++t) acc[t] = (f32x4){0.f, 0.f, 0.f, 0.f};

#pragma unroll
    for (int kb = 0; kb < 4; ++kb) {
        int koff = kb * 32 + kgrp;
        int abyte = (arow * 256 + koff * 2) ^ ((arow & 7) << 4);
        bf16x8 a = *reinterpret_cast<const bf16x8*>(xs + abyte);
#pragma unroll
        for (int t = 0; t < 8; ++t) {
            int c = t * 16 + (lane & 15);
            int bbyte = (c * 256 + koff * 2) ^ ((c & 7) << 4);
            bf16x8 b = *reinterpret_cast<const bf16x8*>(wsm + bbyte);
            acc[t] = __builtin_amdgcn_mfma_f32_16x16x32_bf16(a, b, acc[t], 0, 0, 0);
        }
    }

    // C/D layout: col=lane&15, row=(lane>>4)*4+reg
    int colbase = lane & 15;
    int rgrp = (lane >> 4) * 4;
    float bi[8], al[8];
#pragma unroll
    for (int t = 0; t < 8; ++t) {
        int c = t * 16 + colbase;
        bi[t] = bias[c];
        al[t] = alpha[c];
    }
#pragma unroll
    for (int j = 0; j < 4; ++j) {
        int r = rowbase + lr0 + rgrp + j;
        if (r >= n) continue;
#pragma unroll
        for (int t = 0; t < 8; ++t) {
            int c = t * 16 + colbase;
            float h = acc[t][j];
            if (t == 0 && colbase < D10) {
                // pack pairs (even colbase keeps c,c+1) — partner lane shares r
                float h1 = __shfl_xor(h, 1, 64);
                if ((colbase & 1) == 0) {
                    unsigned int pk = (unsigned int)f2bf(h) |
                                      ((unsigned int)f2bf(h1) << 16);
                    s12b[(size_t)r * 6 + (colbase >> 1)] = pk;
                }
            } else {
                h += bi[t];
                h = h >= 0.f ? h : al[t] * h;
                out[(size_t)r * DIM + c] = h;
            }
        }
    }
}

// ---------------- edge aggregation: ONE 32B sector per edge ----------------
// agg row = 8 u32 (32B aligned): slots 0..5 = pk payload, slot 6 = deg as bf16 1.0.
// 8 lanes per edge; lanes 0..6 all execute the SAME pk-add instruction into
// one contiguous 28B range -> single fabric sector transaction per edge.

__global__ void k_edge_agg(const unsigned int* __restrict__ s12b,
                           const int* __restrict__ row, const int* __restrict__ col,
                           long long total, unsigned int* __restrict__ agg) {
    long long i = (long long)blockIdx.x * blockDim.x + threadIdx.x;
    long long stride = (long long)gridDim.x * blockDim.x;
    for (long long g = i; g < total; g += stride) {
        int e = (int)(g >> 3), l = (int)(g & 7);
        if (l < 7) {
            int r = row[e];
            unsigned int v;
            if (l < 6) v = s12b[(size_t)col[e] * 6 + l];
            else       v = 0x00003F80u;          // bf16(1.0) in low half -> deg count
            atomPkAddBf16(&agg[(size_t)r * 8 + l], v);
        }
    }
}

// ---------------- epilogue for cols 0..11: out = prelu(agg/deg + bias) ----------------

__global__ void k_epi12(const uint4* __restrict__ aggv, const float* __restrict__ bias,
                        const float* __restrict__ alpha, float* __restrict__ out, int n) {
    int r = blockIdx.x * blockDim.x + threadIdx.x;
    if (r >= n) return;
    uint4 a0 = aggv[(size_t)r * 2];        // slots 0..3
    uint4 a1 = aggv[(size_t)r * 2 + 1];    // slots 4..7
    float dg = bf2f(a1.z & 0xFFFFu);       // slot 6 low = degree
    float invd = 1.f / (dg >= 1.f ? dg : 1.f);
    unsigned int s[6] = {a0.x, a0.y, a0.z, a0.w, a1.x, a1.y};
    float h[12];
#pragma unroll
    for (int q = 0; q < 6; ++q) {
        h[2 * q]     = bf2f(s[q] & 0xFFFFu) * invd + bias[2 * q];
        h[2 * q + 1] = bf2f(s[q] >> 16)     * invd + bias[2 * q + 1];
    }
#pragma unroll
    for (int c = 0; c < 12; ++c) {
        float v = h[c];
        h[c] = v >= 0.f ? v : alpha[c] * v;
    }
    float4* o = reinterpret_cast<float4*>(out + (size_t)r * DIM);
    o[0] = make_float4(h[0], h[1], h[2], h[3]);
    o[1] = make_float4(h[4], h[5], h[6], h[7]);
    o[2] = make_float4(h[8], h[9], h[10], h[11]);
}

// ---------------- tier E legacy (tiny workspace fallback) ----------------

__global__ void k_count_deg(const int* __restrict__ row, int E, int* __restrict__ deg) {
    int i = blockIdx.x * blockDim.x + threadIdx.x;
    int stride = gridDim.x * blockDim.x;
    for (; i < E; i += stride) atomicAdd(&deg[row[i]], 1);
}

__global__ void k_edge_atomic(const float4* __restrict__ xv, const int* __restrict__ row,
                              const int* __restrict__ col, int E, float* __restrict__ out) {
    int i = blockIdx.x * blockDim.x + threadIdx.x;
    int stride = gridDim.x * blockDim.x;
    int total = E * 32;
    for (; i < total; i += stride) {
        int e = i >> 5, lane = i & 31;
        int r = row[e], c = col[e];
        float4 v = xv[(size_t)c * 32 + lane];
        float* dst = out + (size_t)r * DIM + lane * 4;
        atomAddF32(dst + 0, v.x);
        atomAddF32(dst + 1, v.y);
        atomAddF32(dst + 2, v.z);
        atomAddF32(dst + 3, v.w);
    }
}

__global__ __launch_bounds__(256) void k_final_legacy(const float4* __restrict__ xv,
                                                      float4* __restrict__ outv,
                                                      const float4* __restrict__ Wv,
                                                      const float4* __restrict__ biasv,
                                                      const float4* __restrict__ alphav,
                                                      const int* __restrict__ deg, int n) {
    __shared__ float4 Ws4[DIM * 32];
    __shared__ float4 vs4[2][32 * 32];

    int tid = threadIdx.x;
    int rowbase = blockIdx.x * 32;
    if (rowbase >= n) return;

    for (int i = tid; i < DIM * 32; i += 256) Ws4[i] = Wv[i];
    for (int i = tid; i < 32 * 32; i += 256) {
        int r = rowbase + (i >> 5);
        if (r < n) {
            vs4[0][i] = outv[(size_t)r * 32 + (i & 31)];
            vs4[1][i] = xv[(size_t)r * 32 + (i & 31)];
        }
    }
    __syncthreads();

    int tx = tid & 31;
    int ty = tid >> 5;
    int r0 = ty * 4;
    const float4* V = (tx < (D10 / 4)) ? vs4[0] : vs4[1];

    float4 acc[4];
#pragma unroll
    for (int r = 0; r < 4; r++) { acc[r].x = acc[r].y = acc[r].z = acc[r].w = 0.f; }

#pragma unroll 8
    for (int k4 = 0; k4 < 32; k4++) {
        float4 w0 = Ws4[(k4 * 4 + 0) * 32 + tx];
        float4 w1 = Ws4[(k4 * 4 + 1) * 32 + tx];
        float4 w2 = Ws4[(k4 * 4 + 2) * 32 + tx];
        float4 w3 = Ws4[(k4 * 4 + 3) * 32 + tx];
#pragma unroll
        for (int r = 0; r < 4; r++) {
            float4 v = V[(r0 + r) * 32 + k4];
            fma4(acc[r], v.x, w0); fma4(acc[r], v.y, w1);
            fma4(acc[r], v.z, w2); fma4(acc[r], v.w, w3);
        }
    }

    float4 b4 = biasv[tx];
    float4 a4 = alphav[tx];
#pragma unroll
    for (int r = 0; r < 4; r++) {
        int row = rowbase + r0 + r;
        if (row >= n) continue;
        float4 h = acc[r];
        if (tx < (D10 / 4)) {
            int d = deg[row];
            float invd = 1.0f / (float)(d > 0 ? d : 1);
            h.x *= invd; h.y *= invd; h.z *= invd; h.w *= invd;
        }
        h.x += b4.x; h.y += b4.y; h.z += b4.z; h.w += b4.w;
        h.x = h.x >= 0.f ? h.x : a4.x * h.x;
        h.y = h.y >= 0.f ? h.y : a4.y * h.y;
        h.z = h.z >= 0.f ? h.z : a4.z * h.z;
        h.w = h.w >= 0.f ? h.w : a4.w * h.w;
        outv[(size_t)row * 32 + tx] = h;
    }
}

// ---------------- launcher ----------------

extern "C" void kernel_launch(void* const* d_in, const int* in_sizes, int n_in,
                              void* d_out, int out_size, void* d_ws, size_t ws_size,
                              hipStream_t stream) {
    const float* x     = (const float*)d_in[0];
    const float* W     = (const float*)d_in[1];
    const float* bias  = (const float*)d_in[2];
    const float* alpha = (const float*)d_in[3];
    const int*   ei    = (const int*)d_in[4];

    int N = in_sizes[0] / DIM;
    int E = in_sizes[4] / 2;
    const int* row = ei;
    const int* col = ei + E;
    float* out = (float*)d_out;

    int gemm_blocks = (N + 63) / 64;
    size_t wt_bytes = (size_t)DIM * DIM * 2;   // 32 KB, 16B/32B-aligned

    // Tier A: Wt | s12b[6N] u32 | agg[8N] u32 (32B-aligned rows)
    size_t need_A = wt_bytes + (size_t)(6 + 8) * N * 4;
    size_t need_E = (size_t)N * 4;

    if (ws_size >= need_A) {
        unsigned short* Wt   = (unsigned short*)d_ws;
        unsigned int* s12b   = (unsigned int*)((char*)d_ws + wt_bytes);
        unsigned int* agg    = s12b + (size_t)6 * N;   // 6N*4 % 32 == 0 -> aligned

        hipMemsetAsync(agg, 0, (size_t)8 * N * sizeof(unsigned int), stream);
        k_wt<<<(DIM * DIM + 255) / 256, 256, 0, stream>>>(W, Wt);
        k_gemm<<<gemm_blocks, 256, 0, stream>>>((const float4*)x, out, (const uint4*)Wt,
                                                bias, alpha, s12b, N);
        long long total = (long long)E * 8;
        k_edge_agg<<<4096, 256, 0, stream>>>(s12b, row, col, total, agg);
        k_epi12<<<(N + 255) / 256, 256, 0, stream>>>((const uint4*)agg, bias, alpha, out, N);
    } else if (ws_size >= need_E) {
        int* deg = (int*)d_ws;
        hipMemsetAsync(out, 0, (size_t)N * DIM * sizeof(float), stream);
        hipMemsetAsync(deg, 0, (size_t)N * sizeof(int), stream);
        k_count_deg<<<2048, 256, 0, stream>>>(row, E, deg);
        k_edge_atomic<<<4096, 256, 0, stream>>>((const float4*)x, row, col, E, out);
        k_final_legacy<<<(N + 31) / 32, 256, 0, stream>>>((const float4*)x, (float4*)out,
                                                          (const float4*)W, (const float4*)bias,
                                                          (const float4*)alpha, deg, N);
    }
}